// Round 3
// baseline (217.693 us; speedup 1.0000x reference)
//
#include <hip/hip_runtime.h>

// PostProcessor3D: threshold(>0.9) + 5x5x5 stride-1 maxpool + strict-local-max
// mask on [64,512,512] fp32. Memory-bound separable stencil.
//
// R3: float4 vectorization + small blocks for latency hiding.
//   - 256-thread blocks (4 waves) -> loose barrier coupling, 4 blocks/CU.
//   - 16 B/lane global loads/stores -> 4x memory-level parallelism.
//   - Tile: W=64 (16 float4), H=16, DCHUNK=16 -> grid 1024 blocks.
// Structure: per D-slice, stage thresholded 20x72-float halo tile in LDS
// (prefetched into regs one slice ahead), W-direction 5-max -> 2nd LDS buffer,
// H-direction 5-max -> register, D-max via 5-entry float4 register ring.
// Padding with 0 == reference -inf padding (thresholded values >= 0, center
// always in window).

#define THRESH 0.9f

constexpr int D = 64, H = 512, W = 512;
constexpr int TW = 64;                    // tile width in floats
constexpr int TH = 16;                    // tile height
constexpr int DCHUNK = 16;                // depth outputs per block
constexpr int HALO = 2;
constexpr int LROWS = TH + 2 * HALO;      // 20 staged rows
constexpr int RAWQ  = TW / 4 + 2;         // 18 quads/row, covers [w0-4, w0+68)
constexpr int RAWQ_S = RAWQ + 1;          // 19: pad to de-phase rows
constexpr int WMQ   = TW / 4;             // 16 quads/row
constexpr int WMQ_S = WMQ + 1;            // 17

__device__ __forceinline__ float4 thresh4(float4 v) {
    v.x = (v.x > THRESH) ? v.x : 0.f;
    v.y = (v.y > THRESH) ? v.y : 0.f;
    v.z = (v.z > THRESH) ? v.z : 0.f;
    v.w = (v.w > THRESH) ? v.w : 0.f;
    return v;
}

__device__ __forceinline__ float4 max4(float4 a, float4 b) {
    return make_float4(fmaxf(a.x, b.x), fmaxf(a.y, b.y),
                       fmaxf(a.z, b.z), fmaxf(a.w, b.w));
}

// 5-tap sliding max over 12 floats (3 quads) -> 4 outputs.
// f[i] = input float at (4*c_out + i); out[j] = max(f[2+j .. 6+j]).
__device__ __forceinline__ float4 wmax5(float4 a, float4 b, float4 c) {
    const float f2 = a.z, f3 = a.w, f4 = b.x, f5 = b.y, f6 = b.z, f7 = b.w;
    const float f8 = c.x, f9 = c.y;
    const float m45 = fmaxf(f4, f5);
    const float m56 = fmaxf(f5, f6);
    const float m345 = fmaxf(f3, m45);
    const float m456 = fmaxf(f4, m56);
    const float m567 = fmaxf(m56, f7);
    const float m678 = fmaxf(fmaxf(f6, f7), f8);
    float4 r;
    r.x = fmaxf(fmaxf(f2, f6), m345);
    r.y = fmaxf(fmaxf(f3, f7), m456);
    r.z = fmaxf(fmaxf(f4, f8), m567);
    r.w = fmaxf(fmaxf(f5, f9), m678);
    return r;
}

__global__ __launch_bounds__(256)
void peak3d_kernel(const float* __restrict__ in, float* __restrict__ out) {
    __shared__ float4 raw[LROWS * RAWQ_S];    // thresholded slice, quad layout
    __shared__ float4 wmax[LROWS * WMQ_S];    // W-direction 5-max

    const int tx = threadIdx.x;               // 0..15 (quad column)
    const int ty = threadIdx.y;               // 0..15 (row)
    const int tid = ty * 16 + tx;             // 0..255

    const int w0 = blockIdx.x * TW;
    const int h0 = blockIdx.y * TH;
    const int d0 = blockIdx.z * DCHUNK;

    // Load mapping: 20 rows x 18 quads = 360 quads, <=2 per thread.
    const int q0 = tid;
    const int q1 = tid + 256;
    const int r0 = q0 / RAWQ, c0 = q0 % RAWQ;
    const int r1 = q1 / RAWQ, c1 = q1 % RAWQ;
    const int lds0 = r0 * RAWQ_S + c0;
    const int lds1 = r1 * RAWQ_S + c1;
    const int gh0 = h0 + r0 - HALO, gw0 = w0 + 4 * c0 - 4;
    const int gh1 = h0 + r1 - HALO, gw1 = w0 + 4 * c1 - 4;
    const bool has1 = (q1 < LROWS * RAWQ);
    const bool ib0 = (gh0 >= 0 && gh0 < H && gw0 >= 0 && gw0 < W);
    const bool ib1 = has1 && (gh1 >= 0 && gh1 < H && gw1 >= 0 && gw1 < W);
    const size_t off0 = ib0 ? ((size_t)gh0 * W + gw0) : 0;
    const size_t off1 = ib1 ? ((size_t)gh1 * W + gw1) : 0;

    const float4 zero4 = make_float4(0.f, 0.f, 0.f, 0.f);
    float4 win[5], cen[5];
#pragma unroll
    for (int k = 0; k < 5; ++k) { win[k] = zero4; cen[k] = zero4; }

    auto loadSlice = [&](int dd, float4& p0, float4& p1) {
        p0 = zero4; p1 = zero4;
        if (dd >= 0 && dd < D) {
            const size_t base = (size_t)dd * (H * W);
            if (ib0) p0 = thresh4(*reinterpret_cast<const float4*>(in + base + off0));
            if (ib1) p1 = thresh4(*reinterpret_cast<const float4*>(in + base + off1));
        }
    };

    float4 p0, p1;
    loadSlice(d0 - HALO, p0, p1);

    const int NS = DCHUNK + 2 * HALO;         // 20 slices
    for (int s = 0; s < NS; ++s) {
        const int ds = d0 - HALO + s;

        // commit prefetched slice to LDS
        raw[lds0] = p0;
        if (has1) raw[lds1] = p1;
        // issue next slice's loads -> hidden behind both barriers + compute
        if (s + 1 < NS) loadSlice(ds + 1, p0, p1);
        __syncthreads();                      // raw ready

        const float4 tc = raw[(ty + HALO) * RAWQ_S + (tx + 1)];

        // W-direction 5-max: 20 rows x 16 quads = 320 items over 256 threads
        {
            int m = tid;
#pragma unroll
            for (int pass = 0; pass < 2; ++pass) {
                if (m < LROWS * WMQ) {
                    const int r = m / WMQ, c = m % WMQ;
                    const float4* rp = &raw[r * RAWQ_S + c];
                    wmax[r * WMQ_S + c] = wmax5(rp[0], rp[1], rp[2]);
                }
                m += 256;
            }
        }
        __syncthreads();                      // wmax ready; all raw reads done

        // H-direction 5-max -> float4 register ring
        const float4* wp = &wmax[ty * WMQ_S + tx];
        float4 hv = wp[0];
        hv = max4(hv, wp[1 * WMQ_S]);
        hv = max4(hv, wp[2 * WMQ_S]);
        hv = max4(hv, wp[3 * WMQ_S]);
        hv = max4(hv, wp[4 * WMQ_S]);

        const int ri = ((ds % 5) + 5) % 5;
        win[ri] = hv;
        cen[ri] = tc;

        if (s >= 4) {
            const int dout = ds - HALO;       // d0 .. d0+15
            const float4 mp = max4(max4(max4(win[0], win[1]),
                                        max4(win[2], win[3])), win[4]);
            const float4 tcc = cen[dout % 5];
            float4 res;
            res.x = (mp.x > 0.f && mp.x == tcc.x) ? mp.x : 0.f;
            res.y = (mp.y > 0.f && mp.y == tcc.y) ? mp.y : 0.f;
            res.z = (mp.z > 0.f && mp.z == tcc.z) ? mp.z : 0.f;
            res.w = (mp.w > 0.f && mp.w == tcc.w) ? mp.w : 0.f;
            *reinterpret_cast<float4*>(
                out + (size_t)dout * (H * W) + (size_t)(h0 + ty) * W + (w0 + 4 * tx)) = res;
        }
        // No 3rd barrier: next iter's raw writes ordered after this iter's raw
        // reads by barrier2; next iter's wmax writes ordered after this iter's
        // wmax reads by its barrier1.
    }
}

extern "C" void kernel_launch(void* const* d_in, const int* in_sizes, int n_in,
                              void* d_out, int out_size, void* d_ws, size_t ws_size,
                              hipStream_t stream) {
    const float* in = (const float*)d_in[0];
    float* out = (float*)d_out;
    dim3 grid(W / TW, H / TH, D / DCHUNK);    // 8 x 32 x 4 = 1024 blocks
    dim3 block(16, 16, 1);
    hipLaunchKernelGGL(peak3d_kernel, grid, block, 0, stream, in, out);
}

// Round 4
// 133.125 us; speedup vs baseline: 1.6353x; 1.6353x over previous
//
#include <hip/hip_runtime.h>

// PostProcessor3D: threshold(>0.9) + 5x5x5 stride-1 maxpool + strict-local-max
// mask on [64,512,512] fp32. Memory-bound separable stencil.
//
// R4: kill the scratch spill. R3's float4 win[5]/cen[5] rings were indexed
// with runtime values (ds%5) -> compiler demoted them to scratch -> 268 MB of
// HBM writes (4x the output) as scratch overflowed L2. The slice loop is now
// j(4) x fully-unrolled k(5), so ring indices (k, (k+3)%5) are compile-time
// constants and the rings stay in VGPRs.
//
// Structure (unchanged from R3): 256-thread blocks, tile W=64 (16 float4),
// H=16, DCHUNK=16, grid 1024. Per D-slice: stage thresholded 20x72 halo tile
// in LDS (prefetched into regs one slice ahead), W-direction 5-max -> 2nd LDS
// buffer, H-direction 5-max -> register, D-max via register ring. Padding with
// 0 == reference -inf padding (thresholded values >= 0, center in window).

#define THRESH 0.9f

constexpr int D = 64, H = 512, W = 512;
constexpr int TW = 64;                    // tile width in floats
constexpr int TH = 16;                    // tile height
constexpr int DCHUNK = 16;                // depth outputs per block
constexpr int HALO = 2;
constexpr int LROWS = TH + 2 * HALO;      // 20 staged rows
constexpr int RAWQ  = TW / 4 + 2;         // 18 quads/row, covers [w0-4, w0+68)
constexpr int RAWQ_S = RAWQ + 1;          // 19: pad to de-phase rows
constexpr int WMQ   = TW / 4;             // 16 quads/row
constexpr int WMQ_S = WMQ + 1;            // 17

__device__ __forceinline__ float4 thresh4(float4 v) {
    v.x = (v.x > THRESH) ? v.x : 0.f;
    v.y = (v.y > THRESH) ? v.y : 0.f;
    v.z = (v.z > THRESH) ? v.z : 0.f;
    v.w = (v.w > THRESH) ? v.w : 0.f;
    return v;
}

__device__ __forceinline__ float4 max4(float4 a, float4 b) {
    return make_float4(fmaxf(a.x, b.x), fmaxf(a.y, b.y),
                       fmaxf(a.z, b.z), fmaxf(a.w, b.w));
}

// 5-tap sliding max over 12 floats (3 quads) -> 4 outputs.
// f[i] = input float at (4*c_out + i); out[j] = max(f[2+j .. 6+j]).
__device__ __forceinline__ float4 wmax5(float4 a, float4 b, float4 c) {
    const float f2 = a.z, f3 = a.w, f4 = b.x, f5 = b.y, f6 = b.z, f7 = b.w;
    const float f8 = c.x, f9 = c.y;
    const float m45 = fmaxf(f4, f5);
    const float m56 = fmaxf(f5, f6);
    const float m345 = fmaxf(f3, m45);
    const float m456 = fmaxf(f4, m56);
    const float m567 = fmaxf(m56, f7);
    const float m678 = fmaxf(fmaxf(f6, f7), f8);
    float4 r;
    r.x = fmaxf(fmaxf(f2, f6), m345);
    r.y = fmaxf(fmaxf(f3, f7), m456);
    r.z = fmaxf(fmaxf(f4, f8), m567);
    r.w = fmaxf(fmaxf(f5, f9), m678);
    return r;
}

__global__ __launch_bounds__(256)
void peak3d_kernel(const float* __restrict__ in, float* __restrict__ out) {
    __shared__ float4 raw[LROWS * RAWQ_S];    // thresholded slice, quad layout
    __shared__ float4 wmax[LROWS * WMQ_S];    // W-direction 5-max

    const int tx = threadIdx.x;               // 0..15 (quad column)
    const int ty = threadIdx.y;               // 0..15 (row)
    const int tid = ty * 16 + tx;             // 0..255

    const int w0 = blockIdx.x * TW;
    const int h0 = blockIdx.y * TH;
    const int d0 = blockIdx.z * DCHUNK;

    // Load mapping: 20 rows x 18 quads = 360 quads, <=2 per thread.
    const int q0 = tid;
    const int q1 = tid + 256;
    const int r0 = q0 / RAWQ, c0 = q0 % RAWQ;
    const int r1 = q1 / RAWQ, c1 = q1 % RAWQ;
    const int lds0 = r0 * RAWQ_S + c0;
    const int lds1 = r1 * RAWQ_S + c1;
    const int gh0 = h0 + r0 - HALO, gw0 = w0 + 4 * c0 - 4;
    const int gh1 = h0 + r1 - HALO, gw1 = w0 + 4 * c1 - 4;
    const bool has1 = (q1 < LROWS * RAWQ);
    const bool ib0 = (gh0 >= 0 && gh0 < H && gw0 >= 0 && gw0 < W);
    const bool ib1 = has1 && (gh1 >= 0 && gh1 < H && gw1 >= 0 && gw1 < W);
    const size_t off0 = ib0 ? ((size_t)gh0 * W + gw0) : 0;
    const size_t off1 = ib1 ? ((size_t)gh1 * W + gw1) : 0;

    const float4 zero4 = make_float4(0.f, 0.f, 0.f, 0.f);
    float4 win[5], cen[5];
#pragma unroll
    for (int k = 0; k < 5; ++k) { win[k] = zero4; cen[k] = zero4; }

    auto loadSlice = [&](int dd, float4& p0, float4& p1) {
        p0 = zero4; p1 = zero4;
        if (dd >= 0 && dd < D) {
            const size_t base = (size_t)dd * (H * W);
            if (ib0) p0 = thresh4(*reinterpret_cast<const float4*>(in + base + off0));
            if (ib1) p1 = thresh4(*reinterpret_cast<const float4*>(in + base + off1));
        }
    };

    float4 p0, p1;
    loadSlice(d0 - HALO, p0, p1);

    // 20 slices = 4 groups of 5; inner loop fully unrolled so all ring
    // indices below are compile-time constants (rings stay in VGPRs).
    for (int j = 0; j < 4; ++j) {
#pragma unroll
        for (int k = 0; k < 5; ++k) {
            const int s = 5 * j + k;              // j dynamic, k constant
            const int ds = d0 - HALO + s;

            // commit prefetched slice to LDS
            raw[lds0] = p0;
            if (has1) raw[lds1] = p1;
            // issue next slice's loads -> hidden behind barriers + compute
            if (s + 1 < DCHUNK + 2 * HALO) loadSlice(ds + 1, p0, p1);
            __syncthreads();                      // raw ready

            const float4 tc = raw[(ty + HALO) * RAWQ_S + (tx + 1)];

            // W-direction 5-max: 20 rows x 16 quads = 320 items / 256 threads
            {
                int m = tid;
#pragma unroll
                for (int pass = 0; pass < 2; ++pass) {
                    if (m < LROWS * WMQ) {
                        const int r = m / WMQ, c = m % WMQ;
                        const float4* rp = &raw[r * RAWQ_S + c];
                        wmax[r * WMQ_S + c] = wmax5(rp[0], rp[1], rp[2]);
                    }
                    m += 256;
                }
            }
            __syncthreads();                      // wmax ready; raw reads done

            // H-direction 5-max -> register ring
            const float4* wp = &wmax[ty * WMQ_S + tx];
            float4 hv = wp[0];
            hv = max4(hv, wp[1 * WMQ_S]);
            hv = max4(hv, wp[2 * WMQ_S]);
            hv = max4(hv, wp[3 * WMQ_S]);
            hv = max4(hv, wp[4 * WMQ_S]);

            win[k] = hv;                          // constant index
            cen[k] = tc;                          // constant index

            if (s >= 4) {
                const int dout = ds - HALO;       // d0 .. d0+15
                const float4 mp = max4(max4(max4(win[0], win[1]),
                                            max4(win[2], win[3])), win[4]);
                const float4 tcc = cen[(k + 3) % 5];   // constant index
                float4 res;
                res.x = (mp.x > 0.f && mp.x == tcc.x) ? mp.x : 0.f;
                res.y = (mp.y > 0.f && mp.y == tcc.y) ? mp.y : 0.f;
                res.z = (mp.z > 0.f && mp.z == tcc.z) ? mp.z : 0.f;
                res.w = (mp.w > 0.f && mp.w == tcc.w) ? mp.w : 0.f;
                *reinterpret_cast<float4*>(
                    out + (size_t)dout * (H * W) + (size_t)(h0 + ty) * W + (w0 + 4 * tx)) = res;
            }
            // No 3rd barrier: next iter's raw writes ordered after this iter's
            // raw reads by barrier2; next iter's wmax writes ordered after
            // this iter's wmax reads by its barrier1.
        }
    }
}

extern "C" void kernel_launch(void* const* d_in, const int* in_sizes, int n_in,
                              void* d_out, int out_size, void* d_ws, size_t ws_size,
                              hipStream_t stream) {
    const float* in = (const float*)d_in[0];
    float* out = (float*)d_out;
    dim3 grid(W / TW, H / TH, D / DCHUNK);    // 8 x 32 x 4 = 1024 blocks
    dim3 block(16, 16, 1);
    hipLaunchKernelGGL(peak3d_kernel, grid, block, 0, stream, in, out);
}

// Round 6
// 122.106 us; speedup vs baseline: 1.7828x; 1.0902x over previous
//
#include <hip/hip_runtime.h>

// PostProcessor3D: threshold(>0.9) + 5x5x5 stride-1 maxpool + strict-local-max
// mask on [64,512,512] fp32. Memory-bound separable stencil.
//
// R6 = R5 with the compile fix: __builtin_nontemporal_store needs a native
// clang vector type, not HIP's float4 class -> store via ext_vector_type(4).
//
// R5 design: one barrier per slice + deeper pipeline + more resident blocks.
//   - raw and wmax LDS both double-buffered; stages software-pipelined:
//     iter t = [stage raw slice t | prefetch t+1] BARRIER [W-max slice t ->
//     wm[t%2], center ring] [H-max slice t-1 from wm[(t-1)%2], D-ring, output
//     slice t-5]. Every LDS RAW/WAR pair is >=1 barrier apart (audited below).
//   - DCHUNK 8: grid 2048 (8 blocks/CU assigned, ~7 resident by LDS) so
//     independent block pipelines cover each other's barrier stalls.
//   - nontemporal float4 output stores (write-only; keep L3 for input halo).
// Ring indices are compile-time constants (5-unrolled k loop) -> no scratch
// spill (R3 lesson). Padding with 0 == reference -inf padding.
//
// Hazard audit (single barrier at end of "stage" phase each iter):
//   wm write@t(W) -> read@t+1(H): 1 barrier.  wm read@t(H, buf t-1) ->
//   rewrite@t+1(W, same buf): 1 barrier.  raw write@t(stage) -> read@t(W):
//   the barrier between.  raw read@t(W, buf t) -> rewrite@t+2(stage): 2
//   barriers.

#define THRESH 0.9f

constexpr int D = 64, H = 512, W = 512;
constexpr int TW = 64;                    // tile width in floats
constexpr int TH = 16;                    // tile height
constexpr int DCHUNK = 8;                 // depth outputs per block
constexpr int HALO = 2;
constexpr int LROWS = TH + 2 * HALO;      // 20 staged rows
constexpr int RAWQ  = TW / 4 + 2;         // 18 quads/row: [w0-4, w0+68)
constexpr int RAWQ_S = RAWQ + 1;          // 19: de-phase rows
constexpr int WMQ   = TW / 4;             // 16 quads/row
constexpr int WMQ_S = WMQ + 1;            // 17
constexpr int NS = DCHUNK + 2 * HALO;     // 12 slices staged per block
constexpr int T_ITERS = NS + 1;           // 13 pipeline iterations

typedef float floatx4 __attribute__((ext_vector_type(4)));  // native vector

__device__ __forceinline__ float4 thresh4(float4 v) {
    v.x = (v.x > THRESH) ? v.x : 0.f;
    v.y = (v.y > THRESH) ? v.y : 0.f;
    v.z = (v.z > THRESH) ? v.z : 0.f;
    v.w = (v.w > THRESH) ? v.w : 0.f;
    return v;
}

__device__ __forceinline__ float4 max4(float4 a, float4 b) {
    return make_float4(fmaxf(a.x, b.x), fmaxf(a.y, b.y),
                       fmaxf(a.z, b.z), fmaxf(a.w, b.w));
}

// 5-tap sliding max over 12 floats (3 quads) -> 4 outputs.
// f[i] = float at (4*c_out + i); out[j] = max(f[2+j .. 6+j]).
__device__ __forceinline__ float4 wmax5(float4 a, float4 b, float4 c) {
    const float f2 = a.z, f3 = a.w, f4 = b.x, f5 = b.y, f6 = b.z, f7 = b.w;
    const float f8 = c.x, f9 = c.y;
    const float m45 = fmaxf(f4, f5);
    const float m56 = fmaxf(f5, f6);
    const float m345 = fmaxf(f3, m45);
    const float m456 = fmaxf(f4, m56);
    const float m567 = fmaxf(m56, f7);
    const float m678 = fmaxf(fmaxf(f6, f7), f8);
    float4 r;
    r.x = fmaxf(fmaxf(f2, f6), m345);
    r.y = fmaxf(fmaxf(f3, f7), m456);
    r.z = fmaxf(fmaxf(f4, f8), m567);
    r.w = fmaxf(fmaxf(f5, f9), m678);
    return r;
}

__global__ __launch_bounds__(256)
void peak3d_kernel(const float* __restrict__ in, float* __restrict__ out) {
    __shared__ float4 raw[2][LROWS * RAWQ_S];   // 2 x 20 x 19 quads = 12160 B
    __shared__ float4 wm [2][LROWS * WMQ_S];    // 2 x 20 x 17 quads = 10880 B

    const int tx = threadIdx.x;               // 0..15 (quad column)
    const int ty = threadIdx.y;               // 0..15 (row)
    const int tid = ty * 16 + tx;

    const int w0 = blockIdx.x * TW;
    const int h0 = blockIdx.y * TH;
    const int d0 = blockIdx.z * DCHUNK;

    // Staging map: 20 rows x 18 quads = 360 quads, <=2 per thread.
    const int q0 = tid;
    const int q1 = tid + 256;
    const int r0 = q0 / RAWQ, c0 = q0 % RAWQ;
    const int r1 = q1 / RAWQ, c1 = q1 % RAWQ;
    const int lds0 = r0 * RAWQ_S + c0;
    const int lds1 = r1 * RAWQ_S + c1;
    const int gh0 = h0 + r0 - HALO, gw0 = w0 + 4 * c0 - 4;
    const int gh1 = h0 + r1 - HALO, gw1 = w0 + 4 * c1 - 4;
    const bool has1 = (q1 < LROWS * RAWQ);
    const bool ib0 = (gh0 >= 0 && gh0 < H && gw0 >= 0 && gw0 < W);
    const bool ib1 = has1 && (gh1 >= 0 && gh1 < H && gw1 >= 0 && gw1 < W);
    const size_t off0 = ib0 ? ((size_t)gh0 * W + gw0) : 0;
    const size_t off1 = ib1 ? ((size_t)gh1 * W + gw1) : 0;

    const float4 zero4 = make_float4(0.f, 0.f, 0.f, 0.f);
    float4 win[5], cen[5];
#pragma unroll
    for (int k = 0; k < 5; ++k) { win[k] = zero4; cen[k] = zero4; }

    auto loadSlice = [&](int dd, float4& p0, float4& p1) {
        p0 = zero4; p1 = zero4;
        if (dd >= 0 && dd < D) {
            const size_t base = (size_t)dd * (H * W);
            if (ib0) p0 = thresh4(*reinterpret_cast<const float4*>(in + base + off0));
            if (ib1) p1 = thresh4(*reinterpret_cast<const float4*>(in + base + off1));
        }
    };

    float4 p0, p1;
    loadSlice(d0 - HALO, p0, p1);             // slice 0

    // t in [0, T_ITERS): groups of 5 so ring indices are constants.
    for (int jj = 0; jj < (T_ITERS + 4) / 5; ++jj) {
#pragma unroll
        for (int k = 0; k < 5; ++k) {
            const int t = 5 * jj + k;
            if (t < T_ITERS) {
                const int buf = t & 1;

                // ---- stage slice t (prefetched last iter) ----
                if (t <= NS - 1) {
                    raw[buf][lds0] = p0;
                    if (has1) raw[buf][lds1] = p1;
                }
                // prefetch slice t+1 (consumed next iteration)
                if (t + 1 <= NS - 1) loadSlice(d0 - HALO + t + 1, p0, p1);

                __syncthreads();              // the ONLY barrier per slice

                // ---- W-stage: wmax + center for slice t ----
                if (t <= NS - 1) {
                    const float4* rp = &raw[buf][ty * RAWQ_S + tx];
                    wm[buf][ty * WMQ_S + tx] = wmax5(rp[0], rp[1], rp[2]);
                    if (tid < (LROWS - TH) * WMQ) {          // 64 tail items
                        const int r = TH + (tid >> 4), c = tid & 15;
                        const float4* rq = &raw[buf][r * RAWQ_S + c];
                        wm[buf][r * WMQ_S + c] = wmax5(rq[0], rq[1], rq[2]);
                    }
                    cen[k] = raw[buf][(ty + HALO) * RAWQ_S + (tx + 1)];
                }

                // ---- H-stage: slice t-1 from the OTHER wm buffer ----
                if (t >= 1) {
                    const float4* wp = &wm[buf ^ 1][ty * WMQ_S + tx];
                    float4 hv = wp[0];
                    hv = max4(hv, wp[1 * WMQ_S]);
                    hv = max4(hv, wp[2 * WMQ_S]);
                    hv = max4(hv, wp[3 * WMQ_S]);
                    hv = max4(hv, wp[4 * WMQ_S]);
                    win[(k + 4) % 5] = hv;    // slice t-1 -> slot (t-1)%5

                    if (t >= 5) {
                        const int dout = d0 + (t - 5);       // 0..DCHUNK-1 local
                        const float4 mp = max4(max4(max4(win[0], win[1]),
                                                    max4(win[2], win[3])), win[4]);
                        const float4 tcc = cen[(k + 2) % 5]; // slice t-3 (center)
                        floatx4 res;
                        res.x = (mp.x > 0.f && mp.x == tcc.x) ? mp.x : 0.f;
                        res.y = (mp.y > 0.f && mp.y == tcc.y) ? mp.y : 0.f;
                        res.z = (mp.z > 0.f && mp.z == tcc.z) ? mp.z : 0.f;
                        res.w = (mp.w > 0.f && mp.w == tcc.w) ? mp.w : 0.f;
                        floatx4* op = reinterpret_cast<floatx4*>(
                            out + (size_t)dout * (H * W) +
                            (size_t)(h0 + ty) * W + (w0 + 4 * tx));
                        __builtin_nontemporal_store(res, op);
                    }
                }
            }
        }
    }
}

extern "C" void kernel_launch(void* const* d_in, const int* in_sizes, int n_in,
                              void* d_out, int out_size, void* d_ws, size_t ws_size,
                              hipStream_t stream) {
    const float* in = (const float*)d_in[0];
    float* out = (float*)d_out;
    dim3 grid(W / TW, H / TH, D / DCHUNK);    // 8 x 32 x 8 = 2048 blocks
    dim3 block(16, 16, 1);
    hipLaunchKernelGGL(peak3d_kernel, grid, block, 0, stream, in, out);
}